// Round 1
// baseline (1088.328 us; speedup 1.0000x reference)
//
#include <hip/hip_runtime.h>
#include <math.h>

constexpr int Fdim = 256;
constexpr int Hdim = 256;
constexpr int Kc   = 16;

__device__ __forceinline__ float selu1(float x){
    const float scale = 1.0507009873554805f;
    const float alpha = 1.6732632423543772f;
    return scale * (x > 0.f ? x : alpha * expm1f(x));
}

// ---------------- CSR build ----------------
__global__ void hist_kernel(const int* __restrict__ src, const int* __restrict__ dst,
                            int* __restrict__ scnt, int* __restrict__ dcnt, int E){
    int i = blockIdx.x * blockDim.x + threadIdx.x;
    if (i < E){
        atomicAdd(&scnt[src[i]], 1);
        atomicAdd(&dcnt[dst[i]], 1);
    }
}

__global__ void scan_kernel(const int* __restrict__ cnt, int* __restrict__ roff, int n){
    __shared__ int sums[1024];
    int t = threadIdx.x;
    int chunk = (n + 1023) / 1024;
    int lo = t * chunk;
    int hi = min(lo + chunk, n);
    int s = 0;
    for (int i = lo; i < hi; ++i) s += cnt[i];
    sums[t] = s;
    __syncthreads();
    for (int off = 1; off < 1024; off <<= 1){
        int v = (t >= off) ? sums[t - off] : 0;
        __syncthreads();
        sums[t] += v;
        __syncthreads();
    }
    int run = sums[t] - s;  // exclusive prefix
    for (int i = lo; i < hi; ++i){ roff[i] = run; run += cnt[i]; }
    if (t == 1023) roff[n] = sums[1023];
}

__global__ void scatter_kernel(const int* __restrict__ src, const int* __restrict__ dst,
                               const float* __restrict__ w, const int* __restrict__ roff,
                               int* __restrict__ cur, int* __restrict__ cdst,
                               float* __restrict__ cw, int E){
    int i = blockIdx.x * blockDim.x + threadIdx.x;
    if (i < E){
        int s = src[i];
        int p = roff[s] + atomicAdd(&cur[s], 1);
        cdst[p] = dst[i];
        cw[p]   = w[i];
    }
}

// ---------------- dense GEMM  [M,256] x [256,256] -> [M,256], fp32 ----------------
__global__ __launch_bounds__(256) void gemm_f32_kernel(const float* __restrict__ A,
                                                       const float* __restrict__ B,
                                                       float* __restrict__ C, int M){
    __shared__ float As[16][72];  // [k][row]
    __shared__ float Bs[16][68];  // [k][col]
    int t  = threadIdx.x;
    int tx = t & 15, ty = t >> 4;
    int bm = blockIdx.x * 64;
    int bn = blockIdx.y * 64;
    float acc[4][4] = {};
    for (int k0 = 0; k0 < 256; k0 += 16){
        {   // A tile: 64 rows x 16 k, float4 per thread
            int row = t >> 2, kc = (t & 3) * 4;
            float4 v = make_float4(0.f,0.f,0.f,0.f);
            if (bm + row < M)
                v = *reinterpret_cast<const float4*>(A + (size_t)(bm + row) * 256 + k0 + kc);
            As[kc+0][row] = v.x; As[kc+1][row] = v.y;
            As[kc+2][row] = v.z; As[kc+3][row] = v.w;
        }
        {   // B tile: 16 k x 64 cols
            int kr = t >> 4, cc = (t & 15) * 4;
            float4 v = *reinterpret_cast<const float4*>(B + (size_t)(k0 + kr) * 256 + bn + cc);
            *reinterpret_cast<float4*>(&Bs[kr][cc]) = v;
        }
        __syncthreads();
        #pragma unroll
        for (int kk = 0; kk < 16; ++kk){
            float4 a = *reinterpret_cast<const float4*>(&As[kk][ty * 4]);
            float4 b = *reinterpret_cast<const float4*>(&Bs[kk][tx * 4]);
            acc[0][0] = fmaf(a.x, b.x, acc[0][0]); acc[0][1] = fmaf(a.x, b.y, acc[0][1]);
            acc[0][2] = fmaf(a.x, b.z, acc[0][2]); acc[0][3] = fmaf(a.x, b.w, acc[0][3]);
            acc[1][0] = fmaf(a.y, b.x, acc[1][0]); acc[1][1] = fmaf(a.y, b.y, acc[1][1]);
            acc[1][2] = fmaf(a.y, b.z, acc[1][2]); acc[1][3] = fmaf(a.y, b.w, acc[1][3]);
            acc[2][0] = fmaf(a.z, b.x, acc[2][0]); acc[2][1] = fmaf(a.z, b.y, acc[2][1]);
            acc[2][2] = fmaf(a.z, b.z, acc[2][2]); acc[2][3] = fmaf(a.z, b.w, acc[2][3]);
            acc[3][0] = fmaf(a.w, b.x, acc[3][0]); acc[3][1] = fmaf(a.w, b.y, acc[3][1]);
            acc[3][2] = fmaf(a.w, b.z, acc[3][2]); acc[3][3] = fmaf(a.w, b.w, acc[3][3]);
        }
        __syncthreads();
    }
    #pragma unroll
    for (int i = 0; i < 4; ++i){
        int row = bm + ty * 4 + i;
        if (row < M){
            float4 v = make_float4(acc[i][0], acc[i][1], acc[i][2], acc[i][3]);
            *reinterpret_cast<float4*>(C + (size_t)row * 256 + bn + tx * 4) = v;
        }
    }
}

// ---------------- SPMM over H=256, + bias + selu (one wave per row) ----------------
__global__ __launch_bounds__(256) void spmm_h_kernel(const float* __restrict__ XW,
        const int* __restrict__ roff, const int* __restrict__ cdst,
        const float* __restrict__ cw, const float* __restrict__ b1,
        float* __restrict__ out, int n){
    int wid = threadIdx.x >> 6, lane = threadIdx.x & 63;
    int r = blockIdx.x * 4 + wid;
    if (r >= n) return;
    int e0 = roff[r], e1 = roff[r + 1];
    float4 acc = make_float4(0.f,0.f,0.f,0.f);
    for (int e = e0; e < e1; ++e){
        int d   = cdst[e];
        float w = cw[e];
        float4 x = *reinterpret_cast<const float4*>(XW + (size_t)d * Hdim + lane * 4);
        acc.x = fmaf(w, x.x, acc.x); acc.y = fmaf(w, x.y, acc.y);
        acc.z = fmaf(w, x.z, acc.z); acc.w = fmaf(w, x.w, acc.w);
    }
    float4 bb = *reinterpret_cast<const float4*>(b1 + lane * 4);
    float4 o;
    o.x = selu1(acc.x + bb.x); o.y = selu1(acc.y + bb.y);
    o.z = selu1(acc.z + bb.z); o.w = selu1(acc.w + bb.w);
    *reinterpret_cast<float4*>(out + (size_t)r * Hdim + lane * 4) = o;
}

// ---------------- GS = gcn_out @ Wk  [N,256]x[256,16] (one wave per row) ----------------
__global__ __launch_bounds__(256) void gemm_k_kernel(const float* __restrict__ G,
        const float* __restrict__ Wk, float* __restrict__ GS, int n){
    __shared__ float ws[Hdim][Kc];  // 16 KB
    int t = threadIdx.x;
    {
        const float4* sp = reinterpret_cast<const float4*>(Wk + (size_t)t * Kc);
        float4* dp = reinterpret_cast<float4*>(&ws[t][0]);
        dp[0] = sp[0]; dp[1] = sp[1]; dp[2] = sp[2]; dp[3] = sp[3];
    }
    __syncthreads();
    int wid = t >> 6, lane = t & 63;
    int q = lane >> 4, k = lane & 15;
    int r = blockIdx.x * 4 + wid;
    if (r >= n) return;
    const float* grow = G + (size_t)r * Hdim;
    float acc = 0.f;
    #pragma unroll 8
    for (int i = 0; i < 64; ++i){
        int h = i * 4 + q;
        acc = fmaf(grow[h], ws[h][k], acc);
    }
    acc += __shfl_xor(acc, 16);
    acc += __shfl_xor(acc, 32);
    if (lane < 16) GS[(size_t)r * Kc + k] = acc;
}

// ---------------- SPMM over K=16 + bias + selu + softmax (16-lane group per row) ----------------
__global__ __launch_bounds__(256) void spmm_k_softmax(const float* __restrict__ GS,
        const int* __restrict__ roff, const int* __restrict__ cdst,
        const float* __restrict__ cw, const float* __restrict__ bsv,
        float* __restrict__ assign, int n){
    int t = threadIdx.x;
    int lane = t & 63;
    int grp = lane >> 4;
    int j = lane & 15;
    int wid = t >> 6;
    int r = blockIdx.x * 16 + wid * 4 + grp;
    if (r >= n) return;
    int e0 = roff[r], e1 = roff[r + 1];
    float acc = 0.f;
    for (int e = e0; e < e1; ++e){
        int d = cdst[e];
        float w = cw[e];
        acc = fmaf(w, GS[(size_t)d * Kc + j], acc);
    }
    float x = selu1(acc + bsv[j]);
    float m = x;
    #pragma unroll
    for (int off = 8; off >= 1; off >>= 1) m = fmaxf(m, __shfl_xor(m, off));
    float ev = expf(x - m);
    float s = ev;
    #pragma unroll
    for (int off = 8; off >= 1; off >>= 1) s += __shfl_xor(s, off);
    assign[(size_t)r * Kc + j] = ev / s;
}

// ---------------- per-node reductions: nl[k], cluster_sizes[k], con_sum ----------------
__global__ __launch_bounds__(256) void node_stats_kernel(const float* __restrict__ as_,
        const float* __restrict__ at_, const int* __restrict__ deg,
        float* __restrict__ red, int n){
    int i = blockIdx.x * blockDim.x + threadIdx.x;
    int lane = threadIdx.x & 63;
    float a[16], b[16];
    float d = 0.f;
    bool valid = (i < n);
    if (valid){
        const float4* pa = reinterpret_cast<const float4*>(as_ + (size_t)i * 16);
        const float4* pb = reinterpret_cast<const float4*>(at_ + (size_t)i * 16);
        #pragma unroll
        for (int q = 0; q < 4; ++q){
            float4 va = pa[q]; float4 vb = pb[q];
            a[q*4+0]=va.x; a[q*4+1]=va.y; a[q*4+2]=va.z; a[q*4+3]=va.w;
            b[q*4+0]=vb.x; b[q*4+1]=vb.y; b[q*4+2]=vb.z; b[q*4+3]=vb.w;
        }
        d = (float)deg[i];
    } else {
        #pragma unroll
        for (int k = 0; k < 16; ++k){ a[k] = 0.f; b[k] = 0.f; }
    }
    float na = 0.f, nb = 0.f, dot = 0.f;
    #pragma unroll
    for (int k = 0; k < 16; ++k){
        na  = fmaf(a[k], a[k], na);
        nb  = fmaf(b[k], b[k], nb);
        dot = fmaf(a[k], b[k], dot);
    }
    float con = 0.f;
    if (valid){
        na = fmaxf(sqrtf(na), 1e-12f);
        nb = fmaxf(sqrtf(nb), 1e-12f);
        con = 2.f - 2.f * dot / (na * nb);  // dot(normalize(a_hat), normalize(a))
    }
    // wave-level butterfly reduce, then one atomic per wave per value
    #pragma unroll
    for (int k = 0; k < 16; ++k){
        float v1 = a[k] * d;   // nl[k] contribution
        float v2 = a[k];       // cluster size contribution
        for (int off = 1; off < 64; off <<= 1){
            v1 += __shfl_xor(v1, off);
            v2 += __shfl_xor(v2, off);
        }
        if (lane == 0){
            atomicAdd(&red[k], v1);
            atomicAdd(&red[16 + k], v2);
        }
    }
    for (int off = 1; off < 64; off <<= 1) con += __shfl_xor(con, off);
    if (lane == 0) atomicAdd(&red[32], con);
}

// ---------------- per-edge trace: sum_e dot(S[src], S[dst]) ----------------
__global__ __launch_bounds__(256) void edge_trace_kernel(const int* __restrict__ src,
        const int* __restrict__ dst, const float* __restrict__ as_,
        float* __restrict__ red, int E){
    int i = blockIdx.x * blockDim.x + threadIdx.x;
    int lane = threadIdx.x & 63;
    float dot = 0.f;
    if (i < E){
        const float4* pa = reinterpret_cast<const float4*>(as_ + (size_t)src[i] * 16);
        const float4* pb = reinterpret_cast<const float4*>(as_ + (size_t)dst[i] * 16);
        #pragma unroll
        for (int q = 0; q < 4; ++q){
            float4 va = pa[q]; float4 vb = pb[q];
            dot = fmaf(va.x, vb.x, dot); dot = fmaf(va.y, vb.y, dot);
            dot = fmaf(va.z, vb.z, dot); dot = fmaf(va.w, vb.w, dot);
        }
    }
    for (int off = 1; off < 64; off <<= 1) dot += __shfl_xor(dot, off);
    if (lane == 0) atomicAdd(&red[33], dot);
}

// ---------------- finalize ----------------
__global__ void finalize_kernel(const float* __restrict__ red, float* __restrict__ out,
                                int n, int E){
    float trace = red[33];
    float nl2 = 0.f, cs2 = 0.f;
    #pragma unroll
    for (int k = 0; k < 16; ++k){
        nl2 = fmaf(red[k], red[k], nl2);
        cs2 = fmaf(red[16 + k], red[16 + k], cs2);
    }
    float twoE = 2.f * (float)E;
    float spectral = -(trace - nl2 / twoE) / twoE;
    float cluster  = sqrtf(cs2) / (float)n * 4.f - 1.f;  // sqrt(K)=4, CLUSTER_REG=1
    float con      = red[32] / (float)n;
    out[0] = spectral + cluster + con;
}

extern "C" void kernel_launch(void* const* d_in, const int* in_sizes, int n_in,
                              void* d_out, int out_size, void* d_ws, size_t ws_size,
                              hipStream_t stream){
    const int*   esrc = (const int*)d_in[0];
    const int*   edst = (const int*)d_in[1];
    const float* ew   = (const float*)d_in[2];
    const float* feat = (const float*)d_in[3];
    const float* faug = (const float*)d_in[4];
    const float* W1   = (const float*)d_in[5];
    const float* b1   = (const float*)d_in[6];
    const float* Wsm  = (const float*)d_in[7];
    const float* bsv  = (const float*)d_in[8];
    const float* Wtm  = (const float*)d_in[9];
    const float* btv  = (const float*)d_in[10];
    int E = in_sizes[0];
    int N = in_sizes[3] / Fdim;

    char* ws = (char*)d_ws;
    size_t off = 0;
    auto alloc = [&](size_t bytes) -> char* {
        char* p = ws + off;
        off = (off + bytes + 255) & ~(size_t)255;
        return p;
    };
    float* XW    = (float*)alloc((size_t)N * Hdim * 4);
    float* GOUT  = (float*)alloc((size_t)N * Hdim * 4);
    float* GS    = (float*)alloc((size_t)N * Kc * 4);
    float* ASG_S = (float*)alloc((size_t)N * Kc * 4);
    float* ASG_T = (float*)alloc((size_t)N * Kc * 4);
    int*   ROFF  = (int*)alloc((size_t)(N + 1) * 4);
    int*   CNT   = (int*)alloc((size_t)N * 4);
    int*   CUR   = (int*)alloc((size_t)N * 4);
    int*   DEG   = (int*)alloc((size_t)N * 4);
    int*   CDST  = (int*)alloc((size_t)E * 4);
    float* CW    = (float*)alloc((size_t)E * 4);
    float* RED   = (float*)alloc(64 * 4);

    hipMemsetAsync(CNT, 0, (size_t)N * 4, stream);
    hipMemsetAsync(CUR, 0, (size_t)N * 4, stream);
    hipMemsetAsync(DEG, 0, (size_t)N * 4, stream);
    hipMemsetAsync(RED, 0, 64 * 4, stream);

    int eb = (E + 255) / 256;
    hist_kernel<<<eb, 256, 0, stream>>>(esrc, edst, CNT, DEG, E);
    scan_kernel<<<1, 1024, 0, stream>>>(CNT, ROFF, N);
    scatter_kernel<<<eb, 256, 0, stream>>>(esrc, edst, ew, ROFF, CUR, CDST, CW, E);

    dim3 gg((N + 63) / 64, Hdim / 64);

    // student branch
    gemm_f32_kernel<<<gg, 256, 0, stream>>>(feat, W1, XW, N);
    spmm_h_kernel<<<(N + 3) / 4, 256, 0, stream>>>(XW, ROFF, CDST, CW, b1, GOUT, N);
    gemm_k_kernel<<<(N + 3) / 4, 256, 0, stream>>>(GOUT, Wsm, GS, N);
    spmm_k_softmax<<<(N + 15) / 16, 256, 0, stream>>>(GS, ROFF, CDST, CW, bsv, ASG_S, N);

    // teacher branch (reuses XW/GOUT/GS scratch)
    gemm_f32_kernel<<<gg, 256, 0, stream>>>(faug, W1, XW, N);
    spmm_h_kernel<<<(N + 3) / 4, 256, 0, stream>>>(XW, ROFF, CDST, CW, b1, GOUT, N);
    gemm_k_kernel<<<(N + 3) / 4, 256, 0, stream>>>(GOUT, Wtm, GS, N);
    spmm_k_softmax<<<(N + 15) / 16, 256, 0, stream>>>(GS, ROFF, CDST, CW, btv, ASG_T, N);

    // loss reductions
    node_stats_kernel<<<(N + 255) / 256, 256, 0, stream>>>(ASG_S, ASG_T, DEG, RED, N);
    edge_trace_kernel<<<eb, 256, 0, stream>>>(esrc, edst, ASG_S, RED, E);
    finalize_kernel<<<1, 1, 0, stream>>>(RED, (float*)d_out, N, E);
}

// Round 2
// 785.189 us; speedup vs baseline: 1.3861x; 1.3861x over previous
//
#include <hip/hip_runtime.h>
#include <math.h>

constexpr int Fdim = 256;
constexpr int Hdim = 256;
constexpr int Kc   = 16;

// reduction slot layout: value v lives at red[v*32] (own 128B cache line)
constexpr int RSTRIDE = 32;
constexpr int NRED    = 34;   // 0..15 nl, 16..31 cluster_sizes, 32 con, 33 trace

__device__ __forceinline__ float selu1(float x){
    const float scale = 1.0507009873554805f;
    const float alpha = 1.6732632423543772f;
    return scale * (x > 0.f ? x : alpha * expm1f(x));
}

// ---------------- CSR build ----------------
__global__ void hist_kernel(const int* __restrict__ src, const int* __restrict__ dst,
                            int* __restrict__ scnt, int* __restrict__ dcnt, int E){
    int i = blockIdx.x * blockDim.x + threadIdx.x;
    if (i < E){
        atomicAdd(&scnt[src[i]], 1);
        atomicAdd(&dcnt[dst[i]], 1);
    }
}

__global__ void scan_kernel(const int* __restrict__ cnt, int* __restrict__ roff, int n){
    __shared__ int sums[1024];
    int t = threadIdx.x;
    int chunk = (n + 1023) / 1024;
    int lo = t * chunk;
    int hi = min(lo + chunk, n);
    int s = 0;
    for (int i = lo; i < hi; ++i) s += cnt[i];
    sums[t] = s;
    __syncthreads();
    for (int off = 1; off < 1024; off <<= 1){
        int v = (t >= off) ? sums[t - off] : 0;
        __syncthreads();
        sums[t] += v;
        __syncthreads();
    }
    int run = sums[t] - s;  // exclusive prefix
    for (int i = lo; i < hi; ++i){ roff[i] = run; run += cnt[i]; }
    if (t == 1023) roff[n] = sums[1023];
}

__global__ void scatter_kernel(const int* __restrict__ src, const int* __restrict__ dst,
                               const float* __restrict__ w, const int* __restrict__ roff,
                               int* __restrict__ cur, int* __restrict__ cdst,
                               float* __restrict__ cw, int E){
    int i = blockIdx.x * blockDim.x + threadIdx.x;
    if (i < E){
        int s = src[i];
        int p = roff[s] + atomicAdd(&cur[s], 1);
        cdst[p] = dst[i];
        cw[p]   = w[i];
    }
}

// ---------------- dense GEMM  [M,256] x [256,256] -> [M,256], fp32 ----------------
__global__ __launch_bounds__(256) void gemm_f32_kernel(const float* __restrict__ A,
                                                       const float* __restrict__ B,
                                                       float* __restrict__ C, int M){
    __shared__ float As[16][72];  // [k][row]
    __shared__ float Bs[16][68];  // [k][col]
    int t  = threadIdx.x;
    int tx = t & 15, ty = t >> 4;
    int bm = blockIdx.x * 64;
    int bn = blockIdx.y * 64;
    float acc[4][4] = {};
    for (int k0 = 0; k0 < 256; k0 += 16){
        {   // A tile: 64 rows x 16 k, float4 per thread
            int row = t >> 2, kc = (t & 3) * 4;
            float4 v = make_float4(0.f,0.f,0.f,0.f);
            if (bm + row < M)
                v = *reinterpret_cast<const float4*>(A + (size_t)(bm + row) * 256 + k0 + kc);
            As[kc+0][row] = v.x; As[kc+1][row] = v.y;
            As[kc+2][row] = v.z; As[kc+3][row] = v.w;
        }
        {   // B tile: 16 k x 64 cols
            int kr = t >> 4, cc = (t & 15) * 4;
            float4 v = *reinterpret_cast<const float4*>(B + (size_t)(k0 + kr) * 256 + bn + cc);
            *reinterpret_cast<float4*>(&Bs[kr][cc]) = v;
        }
        __syncthreads();
        #pragma unroll
        for (int kk = 0; kk < 16; ++kk){
            float4 a = *reinterpret_cast<const float4*>(&As[kk][ty * 4]);
            float4 b = *reinterpret_cast<const float4*>(&Bs[kk][tx * 4]);
            acc[0][0] = fmaf(a.x, b.x, acc[0][0]); acc[0][1] = fmaf(a.x, b.y, acc[0][1]);
            acc[0][2] = fmaf(a.x, b.z, acc[0][2]); acc[0][3] = fmaf(a.x, b.w, acc[0][3]);
            acc[1][0] = fmaf(a.y, b.x, acc[1][0]); acc[1][1] = fmaf(a.y, b.y, acc[1][1]);
            acc[1][2] = fmaf(a.y, b.z, acc[1][2]); acc[1][3] = fmaf(a.y, b.w, acc[1][3]);
            acc[2][0] = fmaf(a.z, b.x, acc[2][0]); acc[2][1] = fmaf(a.z, b.y, acc[2][1]);
            acc[2][2] = fmaf(a.z, b.z, acc[2][2]); acc[2][3] = fmaf(a.z, b.w, acc[2][3]);
            acc[3][0] = fmaf(a.w, b.x, acc[3][0]); acc[3][1] = fmaf(a.w, b.y, acc[3][1]);
            acc[3][2] = fmaf(a.w, b.z, acc[3][2]); acc[3][3] = fmaf(a.w, b.w, acc[3][3]);
        }
        __syncthreads();
    }
    #pragma unroll
    for (int i = 0; i < 4; ++i){
        int row = bm + ty * 4 + i;
        if (row < M){
            float4 v = make_float4(acc[i][0], acc[i][1], acc[i][2], acc[i][3]);
            *reinterpret_cast<float4*>(C + (size_t)row * 256 + bn + tx * 4) = v;
        }
    }
}

// ---------------- SPMM over H=256, + bias + selu (one wave per row) ----------------
__global__ __launch_bounds__(256) void spmm_h_kernel(const float* __restrict__ XW,
        const int* __restrict__ roff, const int* __restrict__ cdst,
        const float* __restrict__ cw, const float* __restrict__ b1,
        float* __restrict__ out, int n){
    int wid = threadIdx.x >> 6, lane = threadIdx.x & 63;
    int r = blockIdx.x * 4 + wid;
    if (r >= n) return;
    int e0 = roff[r], e1 = roff[r + 1];
    float4 acc = make_float4(0.f,0.f,0.f,0.f);
    for (int e = e0; e < e1; ++e){
        int d   = cdst[e];
        float w = cw[e];
        float4 x = *reinterpret_cast<const float4*>(XW + (size_t)d * Hdim + lane * 4);
        acc.x = fmaf(w, x.x, acc.x); acc.y = fmaf(w, x.y, acc.y);
        acc.z = fmaf(w, x.z, acc.z); acc.w = fmaf(w, x.w, acc.w);
    }
    float4 bb = *reinterpret_cast<const float4*>(b1 + lane * 4);
    float4 o;
    o.x = selu1(acc.x + bb.x); o.y = selu1(acc.y + bb.y);
    o.z = selu1(acc.z + bb.z); o.w = selu1(acc.w + bb.w);
    *reinterpret_cast<float4*>(out + (size_t)r * Hdim + lane * 4) = o;
}

// ---------------- GS = gcn_out @ Wk  [N,256]x[256,16] (one wave per row) ----------------
__global__ __launch_bounds__(256) void gemm_k_kernel(const float* __restrict__ G,
        const float* __restrict__ Wk, float* __restrict__ GS, int n){
    __shared__ float ws[Hdim][Kc];  // 16 KB
    int t = threadIdx.x;
    {
        const float4* sp = reinterpret_cast<const float4*>(Wk + (size_t)t * Kc);
        float4* dp = reinterpret_cast<float4*>(&ws[t][0]);
        dp[0] = sp[0]; dp[1] = sp[1]; dp[2] = sp[2]; dp[3] = sp[3];
    }
    __syncthreads();
    int wid = t >> 6, lane = t & 63;
    int q = lane >> 4, k = lane & 15;
    int r = blockIdx.x * 4 + wid;
    if (r >= n) return;
    const float* grow = G + (size_t)r * Hdim;
    float acc = 0.f;
    #pragma unroll 8
    for (int i = 0; i < 64; ++i){
        int h = i * 4 + q;
        acc = fmaf(grow[h], ws[h][k], acc);
    }
    acc += __shfl_xor(acc, 16);
    acc += __shfl_xor(acc, 32);
    if (lane < 16) GS[(size_t)r * Kc + k] = acc;
}

// ---------------- SPMM over K=16 + bias + selu + softmax (16-lane group per row) ----------------
__global__ __launch_bounds__(256) void spmm_k_softmax(const float* __restrict__ GS,
        const int* __restrict__ roff, const int* __restrict__ cdst,
        const float* __restrict__ cw, const float* __restrict__ bsv,
        float* __restrict__ assign, int n){
    int t = threadIdx.x;
    int lane = t & 63;
    int grp = lane >> 4;
    int j = lane & 15;
    int wid = t >> 6;
    int r = blockIdx.x * 16 + wid * 4 + grp;
    if (r >= n) return;
    int e0 = roff[r], e1 = roff[r + 1];
    float acc = 0.f;
    for (int e = e0; e < e1; ++e){
        int d = cdst[e];
        float w = cw[e];
        acc = fmaf(w, GS[(size_t)d * Kc + j], acc);
    }
    float x = selu1(acc + bsv[j]);
    float m = x;
    #pragma unroll
    for (int off = 8; off >= 1; off >>= 1) m = fmaxf(m, __shfl_xor(m, off));
    float ev = expf(x - m);
    float s = ev;
    #pragma unroll
    for (int off = 8; off >= 1; off >>= 1) s += __shfl_xor(s, off);
    assign[(size_t)r * Kc + j] = ev / s;
}

// ---------------- per-node reductions: nl[k], cluster_sizes[k], con_sum ----------------
// Grid-stride; per-thread local accumulation; wave butterfly; LDS block reduce;
// one atomic per block per value, each value on its own 128B line.
__global__ __launch_bounds__(256) void node_stats_kernel(const float* __restrict__ as_,
        const float* __restrict__ at_, const int* __restrict__ deg,
        float* __restrict__ red, int n){
    int tid    = blockIdx.x * blockDim.x + threadIdx.x;
    int stride = gridDim.x * blockDim.x;
    float nl[16] = {}, cs[16] = {};
    float con = 0.f;
    for (int i = tid; i < n; i += stride){
        float a[16], b[16];
        const float4* pa = reinterpret_cast<const float4*>(as_ + (size_t)i * 16);
        const float4* pb = reinterpret_cast<const float4*>(at_ + (size_t)i * 16);
        #pragma unroll
        for (int q = 0; q < 4; ++q){
            float4 va = pa[q]; float4 vb = pb[q];
            a[q*4+0]=va.x; a[q*4+1]=va.y; a[q*4+2]=va.z; a[q*4+3]=va.w;
            b[q*4+0]=vb.x; b[q*4+1]=vb.y; b[q*4+2]=vb.z; b[q*4+3]=vb.w;
        }
        float d = (float)deg[i];
        float na = 0.f, nb = 0.f, dot = 0.f;
        #pragma unroll
        for (int k = 0; k < 16; ++k){
            na  = fmaf(a[k], a[k], na);
            nb  = fmaf(b[k], b[k], nb);
            dot = fmaf(a[k], b[k], dot);
            nl[k] += a[k] * d;
            cs[k] += a[k];
        }
        na = fmaxf(sqrtf(na), 1e-12f);
        nb = fmaxf(sqrtf(nb), 1e-12f);
        con += 2.f - 2.f * dot / (na * nb);
    }
    // wave butterfly for all 33 values
    #pragma unroll
    for (int k = 0; k < 16; ++k){
        #pragma unroll
        for (int off = 1; off < 64; off <<= 1){
            nl[k] += __shfl_xor(nl[k], off);
            cs[k] += __shfl_xor(cs[k], off);
        }
    }
    #pragma unroll
    for (int off = 1; off < 64; off <<= 1) con += __shfl_xor(con, off);

    __shared__ float part[4][40];
    int wid = threadIdx.x >> 6, lane = threadIdx.x & 63;
    if (lane == 0){
        #pragma unroll
        for (int k = 0; k < 16; ++k){
            part[wid][k]      = nl[k];
            part[wid][16 + k] = cs[k];
        }
        part[wid][32] = con;
    }
    __syncthreads();
    int t = threadIdx.x;
    if (t < 33){
        float s = part[0][t] + part[1][t] + part[2][t] + part[3][t];
        atomicAdd(&red[t * RSTRIDE], s);
    }
}

// ---------------- per-edge trace: sum_e dot(S[src], S[dst]) ----------------
__global__ __launch_bounds__(256) void edge_trace_kernel(const int* __restrict__ src,
        const int* __restrict__ dst, const float* __restrict__ as_,
        float* __restrict__ red, int E){
    int tid    = blockIdx.x * blockDim.x + threadIdx.x;
    int stride = gridDim.x * blockDim.x;
    float dot = 0.f;
    for (int i = tid; i < E; i += stride){
        const float4* pa = reinterpret_cast<const float4*>(as_ + (size_t)src[i] * 16);
        const float4* pb = reinterpret_cast<const float4*>(as_ + (size_t)dst[i] * 16);
        #pragma unroll
        for (int q = 0; q < 4; ++q){
            float4 va = pa[q]; float4 vb = pb[q];
            dot = fmaf(va.x, vb.x, dot); dot = fmaf(va.y, vb.y, dot);
            dot = fmaf(va.z, vb.z, dot); dot = fmaf(va.w, vb.w, dot);
        }
    }
    #pragma unroll
    for (int off = 1; off < 64; off <<= 1) dot += __shfl_xor(dot, off);
    __shared__ float part[4];
    int wid = threadIdx.x >> 6, lane = threadIdx.x & 63;
    if (lane == 0) part[wid] = dot;
    __syncthreads();
    if (threadIdx.x == 0)
        atomicAdd(&red[33 * RSTRIDE], part[0] + part[1] + part[2] + part[3]);
}

// ---------------- finalize ----------------
__global__ void finalize_kernel(const float* __restrict__ red, float* __restrict__ out,
                                int n, int E){
    float trace = red[33 * RSTRIDE];
    float nl2 = 0.f, cs2 = 0.f;
    #pragma unroll
    for (int k = 0; k < 16; ++k){
        nl2 = fmaf(red[k * RSTRIDE],        red[k * RSTRIDE],        nl2);
        cs2 = fmaf(red[(16 + k) * RSTRIDE], red[(16 + k) * RSTRIDE], cs2);
    }
    float twoE = 2.f * (float)E;
    float spectral = -(trace - nl2 / twoE) / twoE;
    float cluster  = sqrtf(cs2) / (float)n * 4.f - 1.f;  // sqrt(K)=4, CLUSTER_REG=1
    float con      = red[32 * RSTRIDE] / (float)n;
    out[0] = spectral + cluster + con;
}

extern "C" void kernel_launch(void* const* d_in, const int* in_sizes, int n_in,
                              void* d_out, int out_size, void* d_ws, size_t ws_size,
                              hipStream_t stream){
    const int*   esrc = (const int*)d_in[0];
    const int*   edst = (const int*)d_in[1];
    const float* ew   = (const float*)d_in[2];
    const float* feat = (const float*)d_in[3];
    const float* faug = (const float*)d_in[4];
    const float* W1   = (const float*)d_in[5];
    const float* b1   = (const float*)d_in[6];
    const float* Wsm  = (const float*)d_in[7];
    const float* bsv  = (const float*)d_in[8];
    const float* Wtm  = (const float*)d_in[9];
    const float* btv  = (const float*)d_in[10];
    int E = in_sizes[0];
    int N = in_sizes[3] / Fdim;

    char* ws = (char*)d_ws;
    size_t off = 0;
    auto alloc = [&](size_t bytes) -> char* {
        char* p = ws + off;
        off = (off + bytes + 255) & ~(size_t)255;
        return p;
    };
    float* XW    = (float*)alloc((size_t)N * Hdim * 4);
    float* GOUT  = (float*)alloc((size_t)N * Hdim * 4);
    float* GS    = (float*)alloc((size_t)N * Kc * 4);
    float* ASG_S = (float*)alloc((size_t)N * Kc * 4);
    float* ASG_T = (float*)alloc((size_t)N * Kc * 4);
    int*   ROFF  = (int*)alloc((size_t)(N + 1) * 4);
    int*   CNT   = (int*)alloc((size_t)N * 4);
    int*   CUR   = (int*)alloc((size_t)N * 4);
    int*   DEG   = (int*)alloc((size_t)N * 4);
    int*   CDST  = (int*)alloc((size_t)E * 4);
    float* CW    = (float*)alloc((size_t)E * 4);
    float* RED   = (float*)alloc((size_t)NRED * RSTRIDE * 4);

    hipMemsetAsync(CNT, 0, (size_t)N * 4, stream);
    hipMemsetAsync(CUR, 0, (size_t)N * 4, stream);
    hipMemsetAsync(DEG, 0, (size_t)N * 4, stream);
    hipMemsetAsync(RED, 0, (size_t)NRED * RSTRIDE * 4, stream);

    int eb = (E + 255) / 256;
    hist_kernel<<<eb, 256, 0, stream>>>(esrc, edst, CNT, DEG, E);
    scan_kernel<<<1, 1024, 0, stream>>>(CNT, ROFF, N);
    scatter_kernel<<<eb, 256, 0, stream>>>(esrc, edst, ew, ROFF, CUR, CDST, CW, E);

    dim3 gg((N + 63) / 64, Hdim / 64);

    // student branch
    gemm_f32_kernel<<<gg, 256, 0, stream>>>(feat, W1, XW, N);
    spmm_h_kernel<<<(N + 3) / 4, 256, 0, stream>>>(XW, ROFF, CDST, CW, b1, GOUT, N);
    gemm_k_kernel<<<(N + 3) / 4, 256, 0, stream>>>(GOUT, Wsm, GS, N);
    spmm_k_softmax<<<(N + 15) / 16, 256, 0, stream>>>(GS, ROFF, CDST, CW, bsv, ASG_S, N);

    // teacher branch (reuses XW/GOUT/GS scratch)
    gemm_f32_kernel<<<gg, 256, 0, stream>>>(faug, W1, XW, N);
    spmm_h_kernel<<<(N + 3) / 4, 256, 0, stream>>>(XW, ROFF, CDST, CW, b1, GOUT, N);
    gemm_k_kernel<<<(N + 3) / 4, 256, 0, stream>>>(GOUT, Wtm, GS, N);
    spmm_k_softmax<<<(N + 15) / 16, 256, 0, stream>>>(GS, ROFF, CDST, CW, btv, ASG_T, N);

    // loss reductions
    node_stats_kernel<<<128, 256, 0, stream>>>(ASG_S, ASG_T, DEG, RED, N);
    edge_trace_kernel<<<256, 256, 0, stream>>>(esrc, edst, ASG_S, RED, E);
    finalize_kernel<<<1, 1, 0, stream>>>(RED, (float*)d_out, N, E);
}

// Round 3
// 552.218 us; speedup vs baseline: 1.9708x; 1.4219x over previous
//
#include <hip/hip_runtime.h>
#include <math.h>

constexpr int Fdim = 256;
constexpr int Hdim = 256;
constexpr int Kc   = 16;

constexpr int RSTRIDE = 32;
constexpr int NRED    = 34;   // 0..15 nl, 16..31 cluster_sizes, 32 con, 33 trace

typedef __attribute__((ext_vector_type(8))) short s8v;   // 8 bf16 (4 VGPRs)
typedef __attribute__((ext_vector_type(4))) float f4v;   // 4 fp32 acc

__device__ __forceinline__ float selu1(float x){
    const float scale = 1.0507009873554805f;
    const float alpha = 1.6732632423543772f;
    return scale * (x > 0.f ? x : alpha * expm1f(x));
}

__device__ __forceinline__ ushort f2bf(float x){
    union { float f; unsigned u; } c; c.f = x;
    unsigned r = c.u + 0x7fffu + ((c.u >> 16) & 1u);   // RNE
    return (ushort)(r >> 16);
}

__device__ __forceinline__ float bf2f(ushort b){
    union { unsigned u; float f; } c; c.u = ((unsigned)b) << 16;
    return c.f;
}

// ---------------- CSR build ----------------
__global__ void hist_kernel(const int* __restrict__ src, const int* __restrict__ dst,
                            int* __restrict__ scnt, int* __restrict__ dcnt, int E){
    int i = blockIdx.x * blockDim.x + threadIdx.x;
    if (i < E){
        atomicAdd(&scnt[src[i]], 1);
        atomicAdd(&dcnt[dst[i]], 1);
    }
}

__global__ void scan_kernel(const int* __restrict__ cnt, int* __restrict__ roff, int n){
    __shared__ int sums[1024];
    int t = threadIdx.x;
    int chunk = (n + 1023) / 1024;
    int lo = t * chunk;
    int hi = min(lo + chunk, n);
    int s = 0;
    for (int i = lo; i < hi; ++i) s += cnt[i];
    sums[t] = s;
    __syncthreads();
    for (int off = 1; off < 1024; off <<= 1){
        int v = (t >= off) ? sums[t - off] : 0;
        __syncthreads();
        sums[t] += v;
        __syncthreads();
    }
    int run = sums[t] - s;  // exclusive prefix
    for (int i = lo; i < hi; ++i){ roff[i] = run; run += cnt[i]; }
    if (t == 1023) roff[n] = sums[1023];
}

__global__ void scatter_kernel(const int* __restrict__ src, const int* __restrict__ dst,
                               const float* __restrict__ w, const int* __restrict__ roff,
                               int* __restrict__ cur, int* __restrict__ cdst,
                               float* __restrict__ cw, int E){
    int i = blockIdx.x * blockDim.x + threadIdx.x;
    if (i < E){
        int s = src[i];
        int p = roff[s] + atomicAdd(&cur[s], 1);
        cdst[p] = dst[i];
        cw[p]   = w[i];
    }
}

// ---------------- W1 transpose-cast: Wt[n][k] = bf16(W1[k][n]) ----------------
__global__ void castw_kernel(const float* __restrict__ W, ushort* __restrict__ Wt){
    __shared__ float t[16][17];
    int tx = threadIdx.x, ty = threadIdx.y;
    int k  = blockIdx.y * 16 + ty;
    int nn = blockIdx.x * 16 + tx;
    t[ty][tx] = W[k * 256 + nn];
    __syncthreads();
    int n2 = blockIdx.x * 16 + ty;
    int k2 = blockIdx.y * 16 + tx;
    Wt[n2 * 256 + k2] = f2bf(t[tx][ty]);
}

// ---------------- MFMA bf16 GEMM: C_bf16[M][256] = A_f32[M][256] @ W (Bt[n][k] bf16) ----
// block: 256 thr (4 waves), BM=128 (32 rows/wave), BN=128. grid = (2, ceil(M/128)).
// LDS: Bt slice [128n][256k] bf16 = 64 KB, staged once, XOR-swizzled vs bank conflicts.
__global__ __launch_bounds__(256, 2) void gemm_xw_kernel(
        const float* __restrict__ A, const ushort* __restrict__ Bt,
        ushort* __restrict__ C, int M){
    __shared__ ushort blds[32768];
    int tid = threadIdx.x;
    int n0  = blockIdx.x * 128;
    int bm  = blockIdx.y * 128;

    // stage B slice: 4096 chunks of 16B; chunk c -> n_local = c>>5, kc = c&31
    #pragma unroll
    for (int j = 0; j < 16; ++j){
        int c  = j * 256 + tid;
        int nl = c >> 5, kc = c & 31;
        uint4 v = *reinterpret_cast<const uint4*>(Bt + (((size_t)(n0 + nl)) << 8) + (kc << 3));
        unsigned boff = (unsigned)(((nl << 9) + (kc << 4)) ^ ((nl & 7) << 4));
        *reinterpret_cast<uint4*>(reinterpret_cast<char*>(blds) + boff) = v;
    }
    __syncthreads();

    int w = tid >> 6, l = tid & 63;
    int lr = l & 15, lk = l >> 4;

    f4v acc[2][8];
    #pragma unroll
    for (int m = 0; m < 2; ++m)
        #pragma unroll
        for (int t = 0; t < 8; ++t)
            acc[m][t] = (f4v){0.f, 0.f, 0.f, 0.f};

    int r0 = bm + w * 32 + lr;
    int r1 = r0 + 16;
    int rc0 = min(r0, M - 1), rc1 = min(r1, M - 1);
    const float* a0 = A + (size_t)rc0 * 256 + lk * 8;
    const float* a1 = A + (size_t)rc1 * 256 + lk * 8;

    for (int ks = 0; ks < 8; ++ks){
        s8v af0, af1;
        {
            float4 f0 = *reinterpret_cast<const float4*>(a0 + ks * 32);
            float4 f1 = *reinterpret_cast<const float4*>(a0 + ks * 32 + 4);
            af0[0] = (short)f2bf(f0.x); af0[1] = (short)f2bf(f0.y);
            af0[2] = (short)f2bf(f0.z); af0[3] = (short)f2bf(f0.w);
            af0[4] = (short)f2bf(f1.x); af0[5] = (short)f2bf(f1.y);
            af0[6] = (short)f2bf(f1.z); af0[7] = (short)f2bf(f1.w);
        }
        {
            float4 f0 = *reinterpret_cast<const float4*>(a1 + ks * 32);
            float4 f1 = *reinterpret_cast<const float4*>(a1 + ks * 32 + 4);
            af1[0] = (short)f2bf(f0.x); af1[1] = (short)f2bf(f0.y);
            af1[2] = (short)f2bf(f0.z); af1[3] = (short)f2bf(f0.w);
            af1[4] = (short)f2bf(f1.x); af1[5] = (short)f2bf(f1.y);
            af1[6] = (short)f2bf(f1.z); af1[7] = (short)f2bf(f1.w);
        }
        #pragma unroll
        for (int t = 0; t < 8; ++t){
            int nl = t * 16 + lr;
            unsigned boff = (unsigned)(((nl << 9) + ((ks * 4 + lk) << 4)) ^ ((nl & 7) << 4));
            s8v bf = *reinterpret_cast<const s8v*>(reinterpret_cast<const char*>(blds) + boff);
            acc[0][t] = __builtin_amdgcn_mfma_f32_16x16x32_bf16(af0, bf, acc[0][t], 0, 0, 0);
            acc[1][t] = __builtin_amdgcn_mfma_f32_16x16x32_bf16(af1, bf, acc[1][t], 0, 0, 0);
        }
    }

    // store: row = bm + w*32 + m*16 + lk*4 + j, col = n0 + t*16 + lr
    #pragma unroll
    for (int m = 0; m < 2; ++m){
        #pragma unroll
        for (int t = 0; t < 8; ++t){
            int col = n0 + t * 16 + lr;
            #pragma unroll
            for (int j = 0; j < 4; ++j){
                int row = bm + w * 32 + m * 16 + lk * 4 + j;
                if (row < M) C[(size_t)row * 256 + col] = f2bf(acc[m][t][j]);
            }
        }
    }
}

// ---------------- fused SPMM over H=256 for student+teacher, + bias + selu ----------------
__global__ __launch_bounds__(256) void spmm_h2_kernel(
        const ushort* __restrict__ XWs, const ushort* __restrict__ XWt,
        const int* __restrict__ roff, const int* __restrict__ cdst,
        const float* __restrict__ cw, const float* __restrict__ b1,
        ushort* __restrict__ Gs, ushort* __restrict__ Gt, int n){
    int wid = threadIdx.x >> 6, lane = threadIdx.x & 63;
    int r = blockIdx.x * 4 + wid;
    if (r >= n) return;
    int e0 = roff[r], e1 = roff[r + 1];
    float s0 = 0.f, s1 = 0.f, s2 = 0.f, s3 = 0.f;
    float t0 = 0.f, t1 = 0.f, t2 = 0.f, t3 = 0.f;
    for (int e = e0; e < e1; ++e){
        int d   = cdst[e];
        float w = cw[e];
        ushort4 xs = *reinterpret_cast<const ushort4*>(XWs + (((size_t)d) << 8) + lane * 4);
        ushort4 xt = *reinterpret_cast<const ushort4*>(XWt + (((size_t)d) << 8) + lane * 4);
        s0 = fmaf(w, bf2f(xs.x), s0); s1 = fmaf(w, bf2f(xs.y), s1);
        s2 = fmaf(w, bf2f(xs.z), s2); s3 = fmaf(w, bf2f(xs.w), s3);
        t0 = fmaf(w, bf2f(xt.x), t0); t1 = fmaf(w, bf2f(xt.y), t1);
        t2 = fmaf(w, bf2f(xt.z), t2); t3 = fmaf(w, bf2f(xt.w), t3);
    }
    float4 bb = *reinterpret_cast<const float4*>(b1 + lane * 4);
    ushort4 os = make_ushort4(f2bf(selu1(s0 + bb.x)), f2bf(selu1(s1 + bb.y)),
                              f2bf(selu1(s2 + bb.z)), f2bf(selu1(s3 + bb.w)));
    ushort4 ot = make_ushort4(f2bf(selu1(t0 + bb.x)), f2bf(selu1(t1 + bb.y)),
                              f2bf(selu1(t2 + bb.z)), f2bf(selu1(t3 + bb.w)));
    *reinterpret_cast<ushort4*>(Gs + (((size_t)r) << 8) + lane * 4) = os;
    *reinterpret_cast<ushort4*>(Gt + (((size_t)r) << 8) + lane * 4) = ot;
}

// ---------------- GS = G_bf16 @ Wk  [N,256]x[256,16] (one wave per row) ----------------
__global__ __launch_bounds__(256) void gemm_k_kernel(const ushort* __restrict__ G,
        const float* __restrict__ Wk, float* __restrict__ GS, int n){
    __shared__ float ws[Hdim][Kc];  // 16 KB
    int t = threadIdx.x;
    {
        const float4* sp = reinterpret_cast<const float4*>(Wk + (size_t)t * Kc);
        float4* dp = reinterpret_cast<float4*>(&ws[t][0]);
        dp[0] = sp[0]; dp[1] = sp[1]; dp[2] = sp[2]; dp[3] = sp[3];
    }
    __syncthreads();
    int wid = t >> 6, lane = t & 63;
    int q = lane >> 4, k = lane & 15;
    int r = blockIdx.x * 4 + wid;
    if (r >= n) return;
    const ushort* grow = G + (size_t)r * Hdim;
    float acc = 0.f;
    #pragma unroll 8
    for (int i = 0; i < 64; ++i){
        int h = i * 4 + q;
        acc = fmaf(bf2f(grow[h]), ws[h][k], acc);
    }
    acc += __shfl_xor(acc, 16);
    acc += __shfl_xor(acc, 32);
    if (lane < 16) GS[(size_t)r * Kc + k] = acc;
}

// ---------------- SPMM over K=16 + bias + selu + softmax ----------------
__global__ __launch_bounds__(256) void spmm_k_softmax(const float* __restrict__ GS,
        const int* __restrict__ roff, const int* __restrict__ cdst,
        const float* __restrict__ cw, const float* __restrict__ bsv,
        float* __restrict__ assign, int n){
    int t = threadIdx.x;
    int lane = t & 63;
    int grp = lane >> 4;
    int j = lane & 15;
    int wid = t >> 6;
    int r = blockIdx.x * 16 + wid * 4 + grp;
    if (r >= n) return;
    int e0 = roff[r], e1 = roff[r + 1];
    float acc = 0.f;
    for (int e = e0; e < e1; ++e){
        int d = cdst[e];
        float w = cw[e];
        acc = fmaf(w, GS[(size_t)d * Kc + j], acc);
    }
    float x = selu1(acc + bsv[j]);
    float m = x;
    #pragma unroll
    for (int off = 8; off >= 1; off >>= 1) m = fmaxf(m, __shfl_xor(m, off));
    float ev = expf(x - m);
    float s = ev;
    #pragma unroll
    for (int off = 8; off >= 1; off >>= 1) s += __shfl_xor(s, off);
    assign[(size_t)r * Kc + j] = ev / s;
}

// ---------------- per-node reductions ----------------
__global__ __launch_bounds__(256) void node_stats_kernel(const float* __restrict__ as_,
        const float* __restrict__ at_, const int* __restrict__ deg,
        float* __restrict__ red, int n){
    int tid    = blockIdx.x * blockDim.x + threadIdx.x;
    int stride = gridDim.x * blockDim.x;
    float nl[16] = {}, cs[16] = {};
    float con = 0.f;
    for (int i = tid; i < n; i += stride){
        float a[16], b[16];
        const float4* pa = reinterpret_cast<const float4*>(as_ + (size_t)i * 16);
        const float4* pb = reinterpret_cast<const float4*>(at_ + (size_t)i * 16);
        #pragma unroll
        for (int q = 0; q < 4; ++q){
            float4 va = pa[q]; float4 vb = pb[q];
            a[q*4+0]=va.x; a[q*4+1]=va.y; a[q*4+2]=va.z; a[q*4+3]=va.w;
            b[q*4+0]=vb.x; b[q*4+1]=vb.y; b[q*4+2]=vb.z; b[q*4+3]=vb.w;
        }
        float d = (float)deg[i];
        float na = 0.f, nb = 0.f, dot = 0.f;
        #pragma unroll
        for (int k = 0; k < 16; ++k){
            na  = fmaf(a[k], a[k], na);
            nb  = fmaf(b[k], b[k], nb);
            dot = fmaf(a[k], b[k], dot);
            nl[k] += a[k] * d;
            cs[k] += a[k];
        }
        na = fmaxf(sqrtf(na), 1e-12f);
        nb = fmaxf(sqrtf(nb), 1e-12f);
        con += 2.f - 2.f * dot / (na * nb);
    }
    #pragma unroll
    for (int k = 0; k < 16; ++k){
        #pragma unroll
        for (int off = 1; off < 64; off <<= 1){
            nl[k] += __shfl_xor(nl[k], off);
            cs[k] += __shfl_xor(cs[k], off);
        }
    }
    #pragma unroll
    for (int off = 1; off < 64; off <<= 1) con += __shfl_xor(con, off);

    __shared__ float part[4][40];
    int wid = threadIdx.x >> 6, lane = threadIdx.x & 63;
    if (lane == 0){
        #pragma unroll
        for (int k = 0; k < 16; ++k){
            part[wid][k]      = nl[k];
            part[wid][16 + k] = cs[k];
        }
        part[wid][32] = con;
    }
    __syncthreads();
    int t = threadIdx.x;
    if (t < 33){
        float s = part[0][t] + part[1][t] + part[2][t] + part[3][t];
        atomicAdd(&red[t * RSTRIDE], s);
    }
}

// ---------------- per-edge trace ----------------
__global__ __launch_bounds__(256) void edge_trace_kernel(const int* __restrict__ src,
        const int* __restrict__ dst, const float* __restrict__ as_,
        float* __restrict__ red, int E){
    int tid    = blockIdx.x * blockDim.x + threadIdx.x;
    int stride = gridDim.x * blockDim.x;
    float dot = 0.f;
    for (int i = tid; i < E; i += stride){
        const float4* pa = reinterpret_cast<const float4*>(as_ + (size_t)src[i] * 16);
        const float4* pb = reinterpret_cast<const float4*>(as_ + (size_t)dst[i] * 16);
        #pragma unroll
        for (int q = 0; q < 4; ++q){
            float4 va = pa[q]; float4 vb = pb[q];
            dot = fmaf(va.x, vb.x, dot); dot = fmaf(va.y, vb.y, dot);
            dot = fmaf(va.z, vb.z, dot); dot = fmaf(va.w, vb.w, dot);
        }
    }
    #pragma unroll
    for (int off = 1; off < 64; off <<= 1) dot += __shfl_xor(dot, off);
    __shared__ float part[4];
    int wid = threadIdx.x >> 6, lane = threadIdx.x & 63;
    if (lane == 0) part[wid] = dot;
    __syncthreads();
    if (threadIdx.x == 0)
        atomicAdd(&red[33 * RSTRIDE], part[0] + part[1] + part[2] + part[3]);
}

// ---------------- finalize ----------------
__global__ void finalize_kernel(const float* __restrict__ red, float* __restrict__ out,
                                int n, int E){
    float trace = red[33 * RSTRIDE];
    float nl2 = 0.f, cs2 = 0.f;
    #pragma unroll
    for (int k = 0; k < 16; ++k){
        nl2 = fmaf(red[k * RSTRIDE],        red[k * RSTRIDE],        nl2);
        cs2 = fmaf(red[(16 + k) * RSTRIDE], red[(16 + k) * RSTRIDE], cs2);
    }
    float twoE = 2.f * (float)E;
    float spectral = -(trace - nl2 / twoE) / twoE;
    float cluster  = sqrtf(cs2) / (float)n * 4.f - 1.f;
    float con      = red[32 * RSTRIDE] / (float)n;
    out[0] = spectral + cluster + con;
}

extern "C" void kernel_launch(void* const* d_in, const int* in_sizes, int n_in,
                              void* d_out, int out_size, void* d_ws, size_t ws_size,
                              hipStream_t stream){
    const int*   esrc = (const int*)d_in[0];
    const int*   edst = (const int*)d_in[1];
    const float* ew   = (const float*)d_in[2];
    const float* feat = (const float*)d_in[3];
    const float* faug = (const float*)d_in[4];
    const float* W1   = (const float*)d_in[5];
    const float* b1   = (const float*)d_in[6];
    const float* Wsm  = (const float*)d_in[7];
    const float* bsv  = (const float*)d_in[8];
    const float* Wtm  = (const float*)d_in[9];
    const float* btv  = (const float*)d_in[10];
    int E = in_sizes[0];
    int N = in_sizes[3] / Fdim;

    char* ws = (char*)d_ws;
    size_t off = 0;
    auto alloc = [&](size_t bytes) -> char* {
        char* p = ws + off;
        off = (off + bytes + 255) & ~(size_t)255;
        return p;
    };
    ushort* XWs   = (ushort*)alloc((size_t)N * Hdim * 2);
    ushort* XWt   = (ushort*)alloc((size_t)N * Hdim * 2);
    ushort* Gs    = (ushort*)alloc((size_t)N * Hdim * 2);
    ushort* Gt    = (ushort*)alloc((size_t)N * Hdim * 2);
    float*  GS_s  = (float*)alloc((size_t)N * Kc * 4);
    float*  GS_t  = (float*)alloc((size_t)N * Kc * 4);
    float*  ASG_S = (float*)alloc((size_t)N * Kc * 4);
    float*  ASG_T = (float*)alloc((size_t)N * Kc * 4);
    ushort* WT    = (ushort*)alloc((size_t)256 * 256 * 2);
    int*    ROFF  = (int*)alloc((size_t)(N + 1) * 4);
    int*    CNT   = (int*)alloc((size_t)N * 4);
    int*    CUR   = (int*)alloc((size_t)N * 4);
    int*    DEG   = (int*)alloc((size_t)N * 4);
    int*    CDST  = (int*)alloc((size_t)E * 4);
    float*  CW    = (float*)alloc((size_t)E * 4);
    float*  RED   = (float*)alloc((size_t)NRED * RSTRIDE * 4);

    hipMemsetAsync(CNT, 0, (size_t)N * 4, stream);
    hipMemsetAsync(CUR, 0, (size_t)N * 4, stream);
    hipMemsetAsync(DEG, 0, (size_t)N * 4, stream);
    hipMemsetAsync(RED, 0, (size_t)NRED * RSTRIDE * 4, stream);

    int eb = (E + 255) / 256;
    castw_kernel<<<dim3(16, 16), dim3(16, 16), 0, stream>>>(W1, WT);
    hist_kernel<<<eb, 256, 0, stream>>>(esrc, edst, CNT, DEG, E);
    scan_kernel<<<1, 1024, 0, stream>>>(CNT, ROFF, N);
    scatter_kernel<<<eb, 256, 0, stream>>>(esrc, edst, ew, ROFF, CUR, CDST, CW, E);

    dim3 gg(2, (N + 127) / 128);
    gemm_xw_kernel<<<gg, 256, 0, stream>>>(feat, WT, XWs, N);
    gemm_xw_kernel<<<gg, 256, 0, stream>>>(faug, WT, XWt, N);

    spmm_h2_kernel<<<(N + 3) / 4, 256, 0, stream>>>(XWs, XWt, ROFF, CDST, CW, b1, Gs, Gt, N);

    gemm_k_kernel<<<(N + 3) / 4, 256, 0, stream>>>(Gs, Wsm, GS_s, N);
    spmm_k_softmax<<<(N + 15) / 16, 256, 0, stream>>>(GS_s, ROFF, CDST, CW, bsv, ASG_S, N);
    gemm_k_kernel<<<(N + 3) / 4, 256, 0, stream>>>(Gt, Wtm, GS_t, N);
    spmm_k_softmax<<<(N + 15) / 16, 256, 0, stream>>>(GS_t, ROFF, CDST, CW, btv, ASG_T, N);

    node_stats_kernel<<<128, 256, 0, stream>>>(ASG_S, ASG_T, DEG, RED, N);
    edge_trace_kernel<<<256, 256, 0, stream>>>(esrc, edst, ASG_S, RED, E);
    finalize_kernel<<<1, 1, 0, stream>>>(RED, (float*)d_out, N, E);
}